// Round 7
// baseline (57.959 us; speedup 1.0000x reference)
//
#include <hip/hip_runtime.h>
#include <math.h>

#define A_TOT   18675      // 83*25*9
#define N_PRE   12000
#define N_POST  2000
#define IMG_X   1333.0f
#define IMG_Y   402.0f
#define MIN_SZ  16.0f
#define NMS_T   0.7f
#define NBUCK   4096       // top 12 bits of descending-order key
#define NBLK1   19         // ceil(A_TOT/1024)

// ---------------- K1: decode -> roi,key + per-block partial hist -------------
__global__ __launch_bounds__(1024)
void decode_hist_kernel(const float* __restrict__ anch,
                        const float* __restrict__ cls,
                        const float* __restrict__ pred,
                        float4* __restrict__ roi,
                        unsigned long long* __restrict__ key,
                        unsigned* __restrict__ phist,
                        unsigned* __restrict__ gcnt) {
    __shared__ unsigned lh[NBUCK];
    const int t   = threadIdx.x;
    const int blk = blockIdx.x;
    const int g   = blk * 1024 + t;

#pragma unroll
    for (int e = 0; e < 4; ++e) lh[t + e * 1024] = 0u;
    if (g < NBUCK) gcnt[g] = 0u;          // plain store; K2's atomics come later
    __syncthreads();

    if (g < A_TOT) {
        float ax1 = anch[4*g+0], ay1 = anch[4*g+1], ax2 = anch[4*g+2], ay2 = anch[4*g+3];
        float h_a  = __fsub_rn(ay2, ay1);
        float w_a  = __fsub_rn(ax2, ax1);
        float cy_a = __fadd_rn(ay1, __fmul_rn(0.5f, h_a));
        float cx_a = __fadd_rn(ax1, __fmul_rn(0.5f, w_a));

        float dx = pred[4*g+0], dy = pred[4*g+1], dw = pred[4*g+2], dh = pred[4*g+3];

        float cy = __fadd_rn(__fmul_rn(dy, h_a), cy_a);
        float cx = __fadd_rn(__fmul_rn(dx, w_a), cx_a);
        float h  = __fmul_rn(expf(dh), h_a);
        float w  = __fmul_rn(expf(dw), w_a);

        float hw = __fmul_rn(0.5f, w);
        float hh = __fmul_rn(0.5f, h);
        float x1 = fminf(fmaxf(__fsub_rn(cx, hw), 0.0f), IMG_X);
        float x2 = fminf(fmaxf(__fadd_rn(cx, hw), 0.0f), IMG_X);
        float y1 = fminf(fmaxf(__fsub_rn(cy, hh), 0.0f), IMG_Y);
        float y2 = fminf(fmaxf(__fadd_rn(cy, hh), 0.0f), IMG_Y);

        bool valid = (__fsub_rn(y2, y1) >= MIN_SZ) && (__fsub_rn(x2, x1) >= MIN_SZ);

        roi[g] = make_float4(x1, y1, x2, y2);

        float s = valid ? cls[2*g+1] : -INFINITY;
        unsigned ub   = __float_as_uint(s);
        unsigned mask = ((unsigned)((int)ub >> 31)) | 0x80000000u;
        unsigned ord  = ub ^ mask;          // ascending float order
        unsigned kd   = ~ord;               // descending float order
        key[g] = ((unsigned long long)kd << 32) | (unsigned)g;
        atomicAdd(&lh[kd >> 20], 1u);
    }
    __syncthreads();

    ((uint4*)phist)[blk * 1024 + t] =
        make_uint4(lh[4*t+0], lh[4*t+1], lh[4*t+2], lh[4*t+3]);
}

// ---------------- K2: redundant scan per block + bucket scatter --------------
__global__ __launch_bounds__(1024)
void scan_scatter_kernel(const unsigned long long* __restrict__ key,
                         const unsigned* __restrict__ phist,
                         unsigned* __restrict__ gcnt,
                         unsigned* __restrict__ ghist,
                         unsigned* __restrict__ gbstart,
                         unsigned long long* __restrict__ bkey) {
    __shared__ unsigned bs[NBUCK];
    __shared__ unsigned wsum[16];
    const int t    = threadIdx.x;
    const int blk  = blockIdx.x;
    const int lane = t & 63;
    const int wv   = t >> 6;

    unsigned c0 = 0, c1 = 0, c2 = 0, c3 = 0;
#pragma unroll
    for (int k = 0; k < NBLK1; ++k) {
        uint4 v = ((const uint4*)phist)[k * 1024 + t];
        c0 += v.x; c1 += v.y; c2 += v.z; c3 += v.w;
    }
    unsigned mysum = c0 + c1 + c2 + c3;

    unsigned incl = mysum;
#pragma unroll
    for (int off = 1; off < 64; off <<= 1) {
        unsigned v = __shfl_up(incl, off, 64);
        if (lane >= off) incl += v;
    }
    if (lane == 63) wsum[wv] = incl;
    __syncthreads();
    if (t == 0) {
        unsigned run = 0;
        for (int k = 0; k < 16; ++k) { unsigned v = wsum[k]; wsum[k] = run; run += v; }
    }
    __syncthreads();

    unsigned base = wsum[wv] + (incl - mysum);
    unsigned s0 = base, s1 = s0 + c0, s2 = s1 + c1, s3 = s2 + c2;
    bs[4*t+0] = s0; bs[4*t+1] = s1; bs[4*t+2] = s2; bs[4*t+3] = s3;

    if (blk == 0) {
        ((uint4*)gbstart)[t] = make_uint4(s0, s1, s2, s3);
        ((uint4*)ghist)[t]   = make_uint4(c0, c1, c2, c3);
    }
    __syncthreads();

    int g = blk * 1024 + t;
    if (g < A_TOT) {
        unsigned long long Ki = key[g];
        unsigned b = (unsigned)(Ki >> 52);
        unsigned pos = bs[b] + atomicAdd(&gcnt[b], 1u);
        bkey[pos] = Ki;
    }
}

// ---------------- K3: wave-cooperative exact rank + scatter ------------------
__global__ void rankscatter_kernel(const unsigned long long* __restrict__ bkey,
                                   const unsigned* __restrict__ gbstart,
                                   const unsigned* __restrict__ ghist,
                                   const float4* __restrict__ roi,
                                   float4* __restrict__ sboxes,
                                   float* __restrict__ sareas) {
    int g = blockIdx.x * blockDim.x + threadIdx.x;
    int p = g >> 6;
    int lane = g & 63;
    if (p >= A_TOT) return;

    unsigned long long Ki = bkey[p];
    unsigned b = (unsigned)(Ki >> 52);
    unsigned start = gbstart[b];
    if (start >= N_PRE) return;          // whole bucket past top-N_PRE
    unsigned cnt = ghist[b];

    unsigned r = start;
    for (unsigned m = 0; m < cnt; m += 64) {
        unsigned mm = m + lane;
        bool lt = (mm < cnt) && (bkey[start + mm] < Ki);
        r += (unsigned)__popcll(__ballot(lt));
    }

    if (lane == 0 && r < N_PRE) {
        unsigned idx = (unsigned)Ki;
        float4 bx = roi[idx];
        sboxes[r] = bx;
        sareas[r] = __fmul_rn(__fadd_rn(__fsub_rn(bx.z, bx.x), 1.0f),
                              __fadd_rn(__fsub_rn(bx.w, bx.y), 1.0f));
    }
}

// ---------------- K4: diagonal pair-overlap marking --------------------------
// mark[i] = OR over z in [0, N_PRE-2-i] of IoU(b[z], b[z+i+1]) >= 0.7
__global__ void nms_kernel(const float4* __restrict__ sboxes,
                           const float* __restrict__ sareas,
                           unsigned* __restrict__ mark) {
    int wid  = (blockIdx.x * blockDim.x + threadIdx.x) >> 6;
    int lane = threadIdx.x & 63;
    if (wid >= N_PRE) return;
    const int i      = wid;
    const int npairs = N_PRE - 1 - i;   // z in [0, npairs)

    bool found = false;
    for (int base = 0; base < npairs; base += 64) {
        int z = base + lane;
        bool over = false;
        if (z < npairs) {
            float4 bz = sboxes[z];
            float4 bj = sboxes[z + i + 1];
            float az = sareas[z];
            float aj = sareas[z + i + 1];
            float xx1 = fmaxf(bz.x, bj.x);
            float yy1 = fmaxf(bz.y, bj.y);
            float xx2 = fminf(bz.z, bj.z);
            float yy2 = fminf(bz.w, bj.w);
            float w = fmaxf(0.0f, __fadd_rn(__fsub_rn(xx2, xx1), 1.0f));
            float h = fmaxf(0.0f, __fadd_rn(__fsub_rn(yy2, yy1), 1.0f));
            float inter = __fmul_rn(w, h);
            float denom = __fsub_rn(__fadd_rn(az, aj), inter);
            float ovr   = __fdiv_rn(inter, denom);
            over = (ovr >= NMS_T);
        }
        if (__any(over)) { found = true; break; }
    }
    if (lane == 0) mark[i] = found ? 1u : 0u;
}

// ---------------- K5: compaction + output, 12 blocks, redundant prefix -------
__global__ __launch_bounds__(1024)
void output_kernel(const unsigned* __restrict__ mark,
                   const float4* __restrict__ sboxes,
                   float* __restrict__ out) {
    __shared__ int wsA[16];    // per-wave sums: keeps before my block
    __shared__ int wsB[16];    // per-wave sums: total keeps
    __shared__ int wsS[16];    // per-wave scan sums (own chunk)
    __shared__ int s_base, s_total;
    const int t    = threadIdx.x;
    const int blk  = blockIdx.x;
    const int lane = t & 63;
    const int wv   = t >> 6;
    const int limit = blk * 1024;

    int sum_before = 0, sum_total = 0;
    for (int j = t; j < N_PRE; j += 1024) {
        int k = (mark[j] == 0u) ? 1 : 0;
        sum_total += k;
        if (j < limit) sum_before += k;
    }
#pragma unroll
    for (int off = 32; off > 0; off >>= 1) {
        sum_before += __shfl_xor(sum_before, off, 64);
        sum_total  += __shfl_xor(sum_total,  off, 64);
    }
    if (lane == 0) { wsA[wv] = sum_before; wsB[wv] = sum_total; }
    __syncthreads();
    if (t == 0) {
        int a = 0, b = 0;
        for (int k = 0; k < 16; ++k) { a += wsA[k]; b += wsB[k]; }
        s_base = a; s_total = b;
    }
    __syncthreads();

    const int i = blk * 1024 + t;
    int keep = (i < N_PRE) && (mark[i] == 0u);

    int incl = keep;
#pragma unroll
    for (int off = 1; off < 64; off <<= 1) {
        int v = __shfl_up(incl, off, 64);
        if (lane >= off) incl += v;
    }
    if (lane == 63) wsS[wv] = incl;
    __syncthreads();
    if (t == 0) {
        int run = 0;
        for (int k = 0; k < 16; ++k) { int v = wsS[k]; wsS[k] = run; run += v; }
    }
    __syncthreads();

    int pos = s_base + wsS[wv] + (incl - keep);
    if (keep && pos < N_POST) {
        float4 b4 = sboxes[i];
        out[4*pos+0] = b4.x;
        out[4*pos+1] = b4.y;
        out[4*pos+2] = b4.z;
        out[4*pos+3] = b4.w;
        out[4*N_POST + pos] = 1.0f;
    }
    if (i < N_POST && i >= s_total) {
        out[4*i+0] = 0.0f; out[4*i+1] = 0.0f;
        out[4*i+2] = 0.0f; out[4*i+3] = 0.0f;
        out[4*N_POST + i] = 0.0f;
    }
}

// ---------------- launch ------------------------------------------------------
extern "C" void kernel_launch(void* const* d_in, const int* in_sizes, int n_in,
                              void* d_out, int out_size, void* d_ws, size_t ws_size,
                              hipStream_t stream) {
    const float* anch = (const float*)d_in[0];   // (A,4)
    const float* cls  = (const float*)d_in[1];   // (1,A,2)
    const float* pred = (const float*)d_in[2];   // (1,A,4)
    float* out = (float*)d_out;                  // 8000 rois + 2000 kept

    char* ws = (char*)d_ws;
    float4*             roi     = (float4*)(ws + 0);                   // 298,800
    unsigned long long* key     = (unsigned long long*)(ws + 299008);  // 149,400
    unsigned*           phist   = (unsigned*)(ws + 448512);            // 311,296 (19*16KB)
    unsigned*           gcnt    = (unsigned*)(ws + 759808);            //  16,384
    unsigned*           ghist   = (unsigned*)(ws + 776192);            //  16,384
    unsigned*           gbstart = (unsigned*)(ws + 792576);            //  16,384
    unsigned long long* bkey    = (unsigned long long*)(ws + 808960);  // 149,400
    float4*             sboxes  = (float4*)(ws + 958464);              // 192,000
    float*              sareas  = (float*)(ws + 1150464);              //  48,000
    unsigned*           mark    = (unsigned*)(ws + 1198464);           //  48,000

    const int TB = 256;
    const int rblk = (A_TOT * 64 + TB - 1) / TB;       // 4669

    decode_hist_kernel<<<NBLK1, 1024, 0, stream>>>(anch, cls, pred, roi, key, phist, gcnt);
    scan_scatter_kernel<<<NBLK1, 1024, 0, stream>>>(key, phist, gcnt, ghist, gbstart, bkey);
    rankscatter_kernel<<<rblk, TB, 0, stream>>>(bkey, gbstart, ghist, roi, sboxes, sareas);
    nms_kernel<<<(N_PRE * 64) / TB, TB, 0, stream>>>(sboxes, sareas, mark);
    output_kernel<<<12, 1024, 0, stream>>>(mark, sboxes, out);
}